// Round 1
// baseline (1404.823 us; speedup 1.0000x reference)
//
#include <hip/hip_runtime.h>

// Problem constants (fixed by setup_inputs)
constexpr int Bb = 16, Ll = 2048, Ee = 128, Hh = 256, Dd = 64, Kc = 512, Vv = 4096;
constexpr int NN = Bb * Ll;            // 32768 positions
constexpr int LOGITS = NN * Vv;        // 134217728

// ---------------------------------------------------------------------------
// Weight transpose: w (Cout, Cin, KW) -> wt (KW, Cin, Cout) so GEMM B-tiles
// load coalesced.
__global__ void transpose_w(const float* __restrict__ w, float* __restrict__ wt,
                            int Cout, int Cin, int KW) {
    int i = blockIdx.x * 256 + threadIdx.x;
    int total = Cout * Cin * KW;
    if (i >= total) return;
    int co  = i / (Cin * KW);
    int rem = i - co * (Cin * KW);
    int ci  = rem / KW;
    int k   = rem - ci * KW;
    wt[((size_t)(k * Cin + ci)) * Cout + co] = w[i];
}

// ---------------------------------------------------------------------------
// Embedding gather: out[n, :] = token_emb[x[n], :]  (E=128 -> 32 float4/row)
__global__ void embed_kernel(const int* __restrict__ x,
                             const float4* __restrict__ te,
                             float4* __restrict__ out) {
    int gid = blockIdx.x * 256 + threadIdx.x;   // N*32 total
    int n = gid >> 5;
    int c = gid & 31;
    out[gid] = te[((size_t)x[n] << 5) + c];
}

// ---------------------------------------------------------------------------
// Generic tiled GEMM / conv1d (cross-correlation, pad=(KW-1)/2).
// A: (N, Cin) activations. Wt: (KW, Cin, Cout). Y: (N, Cout).
// Position rows live in batches of L=2048; tile BM divides L so batch edges
// align with tiles; neighbor rows outside [0,L) are zero.
template <int KW, bool RELU, int BM, int BN, int TM, int TN>
__global__ __launch_bounds__(256) void gemm_conv(
    const float* __restrict__ A, const float* __restrict__ Wt,
    const float* __restrict__ bias, float* __restrict__ Y, int Cin, int Cout) {
    constexpr int BK = 16;
    const int tid = threadIdx.x;
    const int tx = tid % (BN / TN);   // 16
    const int ty = tid / (BN / TN);   // 16
    const int n0  = blockIdx.x * BM;
    const int co0 = blockIdx.y * BN;

    __shared__ float As[BK][BM + 4];  // stored transposed: As[c][row]
    __shared__ float Bs[BK][BN];      // Bs[c][col]

    float acc[TM][TN];
#pragma unroll
    for (int i = 0; i < TM; i++)
#pragma unroll
        for (int j = 0; j < TN; j++) acc[i][j] = 0.f;

    constexpr int A4 = BM * BK / (256 * 4);
    constexpr int B4 = BN * BK / (256 * 4);

    for (int k = 0; k < KW; ++k) {
        const int shift = k - (KW - 1) / 2;
        for (int ci0 = 0; ci0 < Cin; ci0 += BK) {
            // ---- stage A tile (transposed into LDS) ----
#pragma unroll
            for (int v = 0; v < A4; ++v) {
                int f4 = v * 256 + tid;          // float4 slot
                int r  = f4 / (BK / 4);          // row in tile
                int c4 = f4 % (BK / 4);          // which float4 of the 16 ci
                int n = n0 + r;
                float4 val = make_float4(0.f, 0.f, 0.f, 0.f);
                if (KW == 1) {
                    val = *(const float4*)(A + (size_t)n * Cin + ci0 + c4 * 4);
                } else {
                    int l  = n & (Ll - 1);
                    int sl = l + shift;
                    if ((unsigned)sl < (unsigned)Ll)
                        val = *(const float4*)(A + (size_t)(n + shift) * Cin + ci0 + c4 * 4);
                }
                As[c4 * 4 + 0][r] = val.x;
                As[c4 * 4 + 1][r] = val.y;
                As[c4 * 4 + 2][r] = val.z;
                As[c4 * 4 + 3][r] = val.w;
            }
            // ---- stage B tile ----
#pragma unroll
            for (int v = 0; v < B4; ++v) {
                int f4 = v * 256 + tid;
                int c  = f4 / (BN / 4);
                int j4 = f4 % (BN / 4);
                float4 w4 = *(const float4*)(Wt + (size_t)(k * Cin + ci0 + c) * Cout + co0 + j4 * 4);
                *(float4*)(&Bs[c][j4 * 4]) = w4;
            }
            __syncthreads();
            // ---- compute ----
#pragma unroll
            for (int cc = 0; cc < BK; ++cc) {
                float a[TM], b[TN];
#pragma unroll
                for (int i = 0; i < TM; i += 4)
                    *(float4*)(&a[i]) = *(const float4*)(&As[cc][ty * TM + i]);
#pragma unroll
                for (int j = 0; j < TN; j += 4)
                    *(float4*)(&b[j]) = *(const float4*)(&Bs[cc][tx * TN + j]);
#pragma unroll
                for (int i = 0; i < TM; i++)
#pragma unroll
                    for (int j = 0; j < TN; j++)
                        acc[i][j] = fmaf(a[i], b[j], acc[i][j]);
            }
            __syncthreads();
        }
    }
    // ---- epilogue: bias (+relu), coalesced float4 stores ----
#pragma unroll
    for (int i = 0; i < TM; i++) {
        int n = n0 + ty * TM + i;
#pragma unroll
        for (int j = 0; j < TN; j += 4) {
            int co = co0 + tx * TN + j;
            float4 r;
            r.x = acc[i][j + 0] + bias[co + 0];
            r.y = acc[i][j + 1] + bias[co + 1];
            r.z = acc[i][j + 2] + bias[co + 2];
            r.w = acc[i][j + 3] + bias[co + 3];
            if (RELU) {
                r.x = fmaxf(r.x, 0.f); r.y = fmaxf(r.y, 0.f);
                r.z = fmaxf(r.z, 0.f); r.w = fmaxf(r.w, 0.f);
            }
            *(float4*)(Y + (size_t)n * Cout + co) = r;
        }
    }
}

// ---------------------------------------------------------------------------
// VQ argmin: per block, 64 rows vs all 512 codes (chunks of 64), D=64.
// dist = sum_d (z-c)^2 ; tie-break = lowest code index (np.argmin semantics).
__global__ __launch_bounds__(256) void vq_kernel(
    const float* __restrict__ ze, const float* __restrict__ cb,
    int* __restrict__ codes_i, float* __restrict__ codes_f) {
    const int tid = threadIdx.x;
    const int tx = tid & 15, ty = tid >> 4;
    const int n0 = blockIdx.x * 64;

    __shared__ float Zs[Dd][64 + 4];   // [d][row]
    __shared__ float Cs[Dd][64 + 4];   // [d][code]
    __shared__ float bD[64][17];
    __shared__ int   bI[64][17];

    // stage z rows (transposed)
#pragma unroll
    for (int v = 0; v < 4; ++v) {
        int f4 = v * 256 + tid;       // 1024 float4
        int row = f4 >> 4, d4 = f4 & 15;
        float4 z = *(const float4*)(ze + (size_t)(n0 + row) * Dd + d4 * 4);
        Zs[d4 * 4 + 0][row] = z.x;
        Zs[d4 * 4 + 1][row] = z.y;
        Zs[d4 * 4 + 2][row] = z.z;
        Zs[d4 * 4 + 3][row] = z.w;
    }

    float best[4];
    int   bidx[4];
#pragma unroll
    for (int i = 0; i < 4; i++) { best[i] = 3.4e38f; bidx[i] = 0; }

    for (int ch = 0; ch < Kc / 64; ++ch) {
        int c0 = ch * 64;
        __syncthreads();
#pragma unroll
        for (int v = 0; v < 4; ++v) {
            int f4 = v * 256 + tid;
            int j = f4 >> 4, d4 = f4 & 15;
            float4 w = *(const float4*)(cb + (size_t)(c0 + j) * Dd + d4 * 4);
            Cs[d4 * 4 + 0][j] = w.x;
            Cs[d4 * 4 + 1][j] = w.y;
            Cs[d4 * 4 + 2][j] = w.z;
            Cs[d4 * 4 + 3][j] = w.w;
        }
        __syncthreads();

        float dist[4][4];
#pragma unroll
        for (int i = 0; i < 4; i++)
#pragma unroll
            for (int j = 0; j < 4; j++) dist[i][j] = 0.f;

#pragma unroll 8
        for (int d = 0; d < Dd; ++d) {
            float a[4], b[4];
            *(float4*)a = *(const float4*)(&Zs[d][ty * 4]);
            *(float4*)b = *(const float4*)(&Cs[d][tx * 4]);
#pragma unroll
            for (int i = 0; i < 4; i++)
#pragma unroll
                for (int j = 0; j < 4; j++) {
                    float df = a[i] - b[j];
                    dist[i][j] = fmaf(df, df, dist[i][j]);
                }
        }
#pragma unroll
        for (int i = 0; i < 4; i++)
#pragma unroll
            for (int j = 0; j < 4; j++) {
                int ci = c0 + tx * 4 + j;
                if (dist[i][j] < best[i]) { best[i] = dist[i][j]; bidx[i] = ci; }
            }
    }
    __syncthreads();
#pragma unroll
    for (int i = 0; i < 4; i++) {
        bD[ty * 4 + i][tx] = best[i];
        bI[ty * 4 + i][tx] = bidx[i];
    }
    __syncthreads();
    if (tid < 64) {
        float bd = bD[tid][0];
        int   bi = bI[tid][0];
        for (int t = 1; t < 16; ++t) {
            float d = bD[tid][t];
            int   ix = bI[tid][t];
            if (d < bd || (d == bd && ix < bi)) { bd = d; bi = ix; }
        }
        codes_i[n0 + tid] = bi;
        codes_f[n0 + tid] = (float)bi;
    }
}

// ---------------------------------------------------------------------------
// z_q gather: zq[n,:] = codebook[codes[n],:]  (D=64 -> 16 float4/row)
__global__ void gather_zq(const int* __restrict__ codes,
                          const float4* __restrict__ cb, float4* __restrict__ zq) {
    int gid = blockIdx.x * 256 + threadIdx.x;  // N*16
    int n = gid >> 4, c = gid & 15;
    zq[gid] = cb[((size_t)codes[n] << 4) + c];
}

// ---------------------------------------------------------------------------
// Commitment loss, two-stage deterministic reduction.
__global__ __launch_bounds__(256) void commit_partial(
    const float* __restrict__ ze, const float* __restrict__ zq,
    float* __restrict__ partial) {
    float s = 0.f;
    for (int i = blockIdx.x * 256 + threadIdx.x; i < NN * Dd; i += 1024 * 256) {
        float d = ze[i] - zq[i];
        s = fmaf(d, d, s);
    }
    for (int off = 32; off; off >>= 1) s += __shfl_down(s, off, 64);
    __shared__ float w[4];
    int lane = threadIdx.x & 63, wv = threadIdx.x >> 6;
    if (lane == 0) w[wv] = s;
    __syncthreads();
    if (threadIdx.x == 0) partial[blockIdx.x] = w[0] + w[1] + w[2] + w[3];
}

__global__ void commit_final(const float* __restrict__ partial, float* __restrict__ loss) {
    float s = 0.f;
    for (int i = threadIdx.x; i < 1024; i += 256) s += partial[i];
    for (int off = 32; off; off >>= 1) s += __shfl_down(s, off, 64);
    __shared__ float w[4];
    int lane = threadIdx.x & 63, wv = threadIdx.x >> 6;
    if (lane == 0) w[wv] = s;
    __syncthreads();
    if (threadIdx.x == 0)
        loss[0] = 0.1f * (w[0] + w[1] + w[2] + w[3]) / (float)(NN * Dd);
}

// ---------------------------------------------------------------------------
extern "C" void kernel_launch(void* const* d_in, const int* in_sizes, int n_in,
                              void* d_out, int out_size, void* d_ws, size_t ws_size,
                              hipStream_t stream) {
    const int*   x    = (const int*)d_in[0];
    const float* te   = (const float*)d_in[1];
    const float* ew1  = (const float*)d_in[2];
    const float* eb1  = (const float*)d_in[3];
    const float* ew2  = (const float*)d_in[4];
    const float* eb2  = (const float*)d_in[5];
    const float* ew3  = (const float*)d_in[6];
    const float* eb3  = (const float*)d_in[7];
    const float* cb   = (const float*)d_in[8];
    const float* dw1  = (const float*)d_in[9];
    const float* db1  = (const float*)d_in[10];
    const float* dw2  = (const float*)d_in[11];
    const float* db2  = (const float*)d_in[12];
    const float* dw3  = (const float*)d_in[13];
    const float* db3  = (const float*)d_in[14];
    const float* outw = (const float*)d_in[15];
    const float* outb = (const float*)d_in[16];

    char* ws = (char*)d_ws;
    size_t off = 0;
    auto alloc = [&](size_t bytes) -> void* {
        void* p = ws + off;
        off = (off + bytes + 255) & ~(size_t)255;
        return p;
    };
    float* bufA   = (float*)alloc((size_t)NN * Ee * 4);  // emb / hd3
    float* bufB   = (float*)alloc((size_t)NN * Hh * 4);  // h1 / hd1
    float* bufC   = (float*)alloc((size_t)NN * Hh * 4);  // h2 / hd2
    float* bufZ   = (float*)alloc((size_t)NN * Dd * 4);  // z_e
    float* bufQ   = (float*)alloc((size_t)NN * Dd * 4);  // z_q
    int*   codesi = (int*)alloc((size_t)NN * 4);
    float* part   = (float*)alloc(1024 * 4);
    float* wt_e1  = (float*)alloc((size_t)3 * Ee * Hh * 4);
    float* wt_e2  = (float*)alloc((size_t)3 * Hh * Hh * 4);
    float* wt_e3  = (float*)alloc((size_t)Hh * Dd * 4);
    float* wt_d1  = (float*)alloc((size_t)Dd * Hh * 4);
    float* wt_d2  = (float*)alloc((size_t)3 * Hh * Hh * 4);
    float* wt_d3  = (float*)alloc((size_t)Hh * Ee * 4);
    float* wt_o   = (float*)alloc((size_t)Ee * Vv * 4);

    float* out       = (float*)d_out;
    float* out_loss  = out + (size_t)LOGITS;
    float* out_codes = out_loss + 1;

    auto tg = [](int n) { return dim3((n + 255) / 256); };
    transpose_w<<<tg(Hh * Ee * 3), 256, 0, stream>>>(ew1, wt_e1, Hh, Ee, 3);
    transpose_w<<<tg(Hh * Hh * 3), 256, 0, stream>>>(ew2, wt_e2, Hh, Hh, 3);
    transpose_w<<<tg(Dd * Hh),     256, 0, stream>>>(ew3, wt_e3, Dd, Hh, 1);
    transpose_w<<<tg(Hh * Dd),     256, 0, stream>>>(dw1, wt_d1, Hh, Dd, 1);
    transpose_w<<<tg(Hh * Hh * 3), 256, 0, stream>>>(dw2, wt_d2, Hh, Hh, 3);
    transpose_w<<<tg(Ee * Hh),     256, 0, stream>>>(dw3, wt_d3, Ee, Hh, 1);
    transpose_w<<<tg(Vv * Ee),     256, 0, stream>>>(outw, wt_o, Vv, Ee, 1);

    embed_kernel<<<dim3(NN * 32 / 256), 256, 0, stream>>>(x, (const float4*)te, (float4*)bufA);

    // Encoder (fp32 to keep VQ argmin exact)
    gemm_conv<3, true, 128, 128, 8, 8><<<dim3(NN / 128, Hh / 128), 256, 0, stream>>>(bufA, wt_e1, eb1, bufB, Ee, Hh);
    gemm_conv<3, true, 128, 128, 8, 8><<<dim3(NN / 128, Hh / 128), 256, 0, stream>>>(bufB, wt_e2, eb2, bufC, Hh, Hh);
    gemm_conv<1, false, 64, 64, 4, 4><<<dim3(NN / 64, 1), 256, 0, stream>>>(bufC, wt_e3, eb3, bufZ, Hh, Dd);

    // VQ
    vq_kernel<<<dim3(NN / 64), 256, 0, stream>>>(bufZ, cb, codesi, out_codes);
    gather_zq<<<dim3(NN * 16 / 256), 256, 0, stream>>>(codesi, (const float4*)cb, (float4*)bufQ);
    commit_partial<<<dim3(1024), 256, 0, stream>>>(bufZ, bufQ, part);
    commit_final<<<dim3(1), 256, 0, stream>>>(part, out_loss);

    // Decoder
    gemm_conv<1, true, 128, 128, 8, 8><<<dim3(NN / 128, Hh / 128), 256, 0, stream>>>(bufQ, wt_d1, db1, bufB, Dd, Hh);
    gemm_conv<3, true, 128, 128, 8, 8><<<dim3(NN / 128, Hh / 128), 256, 0, stream>>>(bufB, wt_d2, db2, bufC, Hh, Hh);
    gemm_conv<1, true, 128, 128, 8, 8><<<dim3(NN / 128, Ee / 128), 256, 0, stream>>>(bufC, wt_d3, db3, bufA, Hh, Ee);

    // Vocab projection -> logits
    gemm_conv<1, false, 128, 128, 8, 8><<<dim3(NN / 128, Vv / 128), 256, 0, stream>>>(bufA, wt_o, outb, out, Ee, Vv);
}